// Round 2
// baseline (4918.419 us; speedup 1.0000x reference)
//
#include <hip/hip_runtime.h>
#include <hip/hip_cooperative_groups.h>
#include <math.h>

namespace cg = cooperative_groups;

#define N_PTS 8192
#define M_PTS 2048
#define D_DIM 768
#define EPS_F 0.0025f
#define INV_EPS_F 400.0f
#define SINK_ITERS 50
#define QSCALE_F 12800.0f       // INV_EPS * 32
#define DQ_F (1.0f / 32.0f)     // dequant: z uses q * DQ in exponent units

// ---------------------------------------------------------------------------
// init: la = log(h) (rows 0..N-1), lb = log(hi) (rows N..N+M-1), g = 0
// ---------------------------------------------------------------------------
__global__ __launch_bounds__(256) void sk_init_logs(
    const float* __restrict__ h, const float* __restrict__ hi,
    float* __restrict__ lw, float* __restrict__ g)
{
    const int t = blockIdx.x * 256 + threadIdx.x;
    if (t < N_PTS)               lw[t] = logf(h[t]);
    else if (t < N_PTS + M_PTS)  lw[t] = logf(hi[t - N_PTS]);
    if (t < M_PTS)               g[t] = 0.f;
}

// ---------------------------------------------------------------------------
// Tiled fp32 GEMM: O[r,s] = dot(A[r,:], B[s,:]) over K = D_DIM (A.B^T, NT).
// MODE 0: plain fp32 write (x = d @ W^T, y = si @ W^T)
// MODE 1: cost epilogue C = relu(xs[r]+ys[s]-dot), quantized to uint16
//         exponent units (C*12800); writes Q and Q^T.
// ---------------------------------------------------------------------------
template<int MODE>
__global__ __launch_bounds__(256) void sk_gemm_nt(
    const float* __restrict__ A, const float* __restrict__ B,
    float* __restrict__ O, unsigned short* __restrict__ Q,
    unsigned short* __restrict__ QT,
    const float* __restrict__ xs, const float* __restrict__ ys,
    const int R, const int S)
{
    __shared__ float As[16][68];
    __shared__ float Bs[16][68];
    const int tid  = threadIdx.x;
    const int ty   = tid >> 4;        // 0..15
    const int tx   = tid & 15;        // 0..15
    const int row0 = blockIdx.y * 64;
    const int col0 = blockIdx.x * 64;
    const int lrow = tid >> 2;        // 0..63
    const int lk4  = (tid & 3) << 2;  // 0,4,8,12
    const float* Ap = A + (size_t)(row0 + lrow) * D_DIM + lk4;
    const float* Bp = B + (size_t)(col0 + lrow) * D_DIM + lk4;
    float acc[4][4] = {};

    for (int k0 = 0; k0 < D_DIM; k0 += 16) {
        const float4 av = *(const float4*)(Ap + k0);
        const float4 bv = *(const float4*)(Bp + k0);
        __syncthreads();
        As[lk4 + 0][lrow] = av.x; As[lk4 + 1][lrow] = av.y;
        As[lk4 + 2][lrow] = av.z; As[lk4 + 3][lrow] = av.w;
        Bs[lk4 + 0][lrow] = bv.x; Bs[lk4 + 1][lrow] = bv.y;
        Bs[lk4 + 2][lrow] = bv.z; Bs[lk4 + 3][lrow] = bv.w;
        __syncthreads();
        #pragma unroll
        for (int kk = 0; kk < 16; ++kk) {
            const float a0 = As[kk][ty * 4 + 0], a1 = As[kk][ty * 4 + 1],
                        a2 = As[kk][ty * 4 + 2], a3 = As[kk][ty * 4 + 3];
            const float b0 = Bs[kk][tx * 4 + 0], b1 = Bs[kk][tx * 4 + 1],
                        b2 = Bs[kk][tx * 4 + 2], b3 = Bs[kk][tx * 4 + 3];
            acc[0][0] = fmaf(a0, b0, acc[0][0]); acc[0][1] = fmaf(a0, b1, acc[0][1]);
            acc[0][2] = fmaf(a0, b2, acc[0][2]); acc[0][3] = fmaf(a0, b3, acc[0][3]);
            acc[1][0] = fmaf(a1, b0, acc[1][0]); acc[1][1] = fmaf(a1, b1, acc[1][1]);
            acc[1][2] = fmaf(a1, b2, acc[1][2]); acc[1][3] = fmaf(a1, b3, acc[1][3]);
            acc[2][0] = fmaf(a2, b0, acc[2][0]); acc[2][1] = fmaf(a2, b1, acc[2][1]);
            acc[2][2] = fmaf(a2, b2, acc[2][2]); acc[2][3] = fmaf(a2, b3, acc[2][3]);
            acc[3][0] = fmaf(a3, b0, acc[3][0]); acc[3][1] = fmaf(a3, b1, acc[3][1]);
            acc[3][2] = fmaf(a3, b2, acc[3][2]); acc[3][3] = fmaf(a3, b3, acc[3][3]);
        }
    }

    if (MODE == 0) {
        #pragma unroll
        for (int i = 0; i < 4; ++i) {
            const float4 v = make_float4(acc[i][0], acc[i][1], acc[i][2], acc[i][3]);
            *(float4*)(O + (size_t)(row0 + ty * 4 + i) * S + col0 + tx * 4) = v;
        }
    } else {
        float xv[4], yv[4];
        #pragma unroll
        for (int i = 0; i < 4; ++i) xv[i] = xs[row0 + ty * 4 + i];
        #pragma unroll
        for (int j = 0; j < 4; ++j) yv[j] = ys[col0 + tx * 4 + j];
        unsigned short qv[4][4];
        #pragma unroll
        for (int i = 0; i < 4; ++i)
            #pragma unroll
            for (int j = 0; j < 4; ++j) {
                const float cv = fmaxf(xv[i] + yv[j] - acc[i][j], 0.f);
                qv[i][j] = (unsigned short)fminf(fmaf(cv, QSCALE_F, 0.5f), 65535.f);
            }
        #pragma unroll
        for (int i = 0; i < 4; ++i) {
            const ushort4 v = make_ushort4(qv[i][0], qv[i][1], qv[i][2], qv[i][3]);
            *(ushort4*)(Q + (size_t)(row0 + ty * 4 + i) * S + col0 + tx * 4) = v;
        }
        #pragma unroll
        for (int j = 0; j < 4; ++j) {
            const ushort4 w = make_ushort4(qv[0][j], qv[1][j], qv[2][j], qv[3][j]);
            *(ushort4*)(QT + (size_t)(col0 + tx * 4 + j) * R + row0 + ty * 4) = w;
        }
    }
}

// ---------------------------------------------------------------------------
// xs[r] = 0.5 * ||X[r,:]||^2 ; one wave per row, 4 rows per block
// ---------------------------------------------------------------------------
__global__ __launch_bounds__(256) void sk_row_norms(
    const float* __restrict__ X, float* __restrict__ XS)
{
    const int row  = blockIdx.x * 4 + (threadIdx.x >> 6);
    const int lane = threadIdx.x & 63;
    const float* p = X + (size_t)row * D_DIM;
    float s = 0.f;
    #pragma unroll
    for (int k = lane; k < D_DIM; k += 64) { const float v = p[k]; s = fmaf(v, v, s); }
    #pragma unroll
    for (int off = 32; off; off >>= 1) s += __shfl_xor(s, off, 64);
    if (lane == 0) XS[row] = 0.5f * s;
}

// ---------------------------------------------------------------------------
// helpers for the fused Sinkhorn
// ---------------------------------------------------------------------------
__device__ __forceinline__ void sk_unpack8(
    const uint4 v, const float4 h0, const float4 h1, float* z)
{
    z[0] = fmaf((float)(v.x & 0xffffu), -DQ_F, h0.x);
    z[1] = fmaf((float)(v.x >> 16),     -DQ_F, h0.y);
    z[2] = fmaf((float)(v.y & 0xffffu), -DQ_F, h0.z);
    z[3] = fmaf((float)(v.y >> 16),     -DQ_F, h0.w);
    z[4] = fmaf((float)(v.z & 0xffffu), -DQ_F, h1.x);
    z[5] = fmaf((float)(v.z >> 16),     -DQ_F, h1.y);
    z[6] = fmaf((float)(v.w & 0xffffu), -DQ_F, h1.z);
    z[7] = fmaf((float)(v.w >> 16),     -DQ_F, h1.w);
}

__device__ __forceinline__ void sk_merge(float& m, float& s, float mc, float sc)
{
    const float nm = fmaxf(m, mc);
    s = s * __expf(m - nm) + sc * __expf(mc - nm);
    m = nm;
}

// ---------------------------------------------------------------------------
// Fused 50-iteration log-domain Sinkhorn + final extrapolation.
// Cooperative launch: 256 blocks x 1024 threads (1 block/CU).
// Phase F: F[i] = -eps*LSE_j( lb[j]+G[j]/eps - Q[i,j]*DQ ), 32 rows/block.
// Phase G: G[j] = -eps*LSE_i( la[i]+F[i]/eps - QT[j,i]*DQ ), 8 rows/block,
//          2 waves per row (half each), merged via LDS.
// Note g_out of the reference == G after iteration 50, so only the extra
// F-phase (-> FO) is run at the end.
// ---------------------------------------------------------------------------
__global__ __launch_bounds__(1024) void sk_sinkhorn_coop(
    const unsigned short* __restrict__ Q,
    const unsigned short* __restrict__ QT,
    const float* __restrict__ LW,
    float* __restrict__ F, float* __restrict__ G, float* __restrict__ FO)
{
    cg::grid_group grid = cg::this_grid();
    __shared__ __align__(16) float hb[N_PTS];   // 32 KB, reused per phase
    __shared__ float mred[8], sred[8];
    const int tid  = threadIdx.x;
    const int b    = blockIdx.x;
    const int wave = tid >> 6;
    const int lane = tid & 63;

    for (int it = 0; it <= SINK_ITERS; ++it) {
        // ---------- phase F ----------
        for (int j = tid; j < M_PTS; j += 1024)
            hb[j] = fmaf(G[j], INV_EPS_F, LW[N_PTS + j]);
        __syncthreads();

        float* dstF = (it == SINK_ITERS) ? FO : F;
        #pragma unroll
        for (int rr = 0; rr < 2; ++rr) {
            const int row = b * 32 + wave * 2 + rr;
            const uint4* qp = (const uint4*)(Q + (size_t)row * M_PTS);
            float z[32];
            #pragma unroll
            for (int ld = 0; ld < 4; ++ld) {
                const uint4 v = qp[ld * 64 + lane];
                const int cb = (ld * 64 + lane) * 8;
                const float4 h0 = *(const float4*)&hb[cb];
                const float4 h1 = *(const float4*)&hb[cb + 4];
                sk_unpack8(v, h0, h1, &z[ld * 8]);
            }
            float m = z[0];
            #pragma unroll
            for (int k = 1; k < 32; ++k) m = fmaxf(m, z[k]);
            float s = 0.f;
            #pragma unroll
            for (int k = 0; k < 32; ++k) s += __expf(z[k] - m);
            #pragma unroll
            for (int off = 1; off < 64; off <<= 1) {
                const float m2 = __shfl_xor(m, off, 64);
                const float s2 = __shfl_xor(s, off, 64);
                sk_merge(m, s, m2, s2);
            }
            if (lane == 0) dstF[row] = -EPS_F * (m + __logf(s));
        }
        if (it == SINK_ITERS) break;
        grid.sync();

        // ---------- phase G ----------
        for (int j = tid; j < N_PTS; j += 1024)
            hb[j] = fmaf(F[j], INV_EPS_F, LW[j]);
        __syncthreads();

        const int grow = b * 8 + (wave & 7);
        const int half = wave >> 3;
        const uint4* qp = (const uint4*)(QT + (size_t)grow * N_PTS + half * 4096);
        float m = -INFINITY, s = 0.f;
        #pragma unroll
        for (int ch = 0; ch < 2; ++ch) {
            float z[32];
            #pragma unroll
            for (int ld = 0; ld < 4; ++ld) {
                const uint4 v = qp[ch * 256 + ld * 64 + lane];
                const int cb = half * 4096 + (ch * 2048) + (ld * 64 + lane) * 8;
                const float4 h0 = *(const float4*)&hb[cb];
                const float4 h1 = *(const float4*)&hb[cb + 4];
                sk_unpack8(v, h0, h1, &z[ld * 8]);
            }
            float mc = z[0];
            #pragma unroll
            for (int k = 1; k < 32; ++k) mc = fmaxf(mc, z[k]);
            float sc = 0.f;
            #pragma unroll
            for (int k = 0; k < 32; ++k) sc += __expf(z[k] - mc);
            sk_merge(m, s, mc, sc);
        }
        #pragma unroll
        for (int off = 1; off < 64; off <<= 1) {
            const float m2 = __shfl_xor(m, off, 64);
            const float s2 = __shfl_xor(s, off, 64);
            sk_merge(m, s, m2, s2);
        }
        if (half == 1 && lane == 0) { mred[wave & 7] = m; sred[wave & 7] = s; }
        __syncthreads();
        if (half == 0 && lane == 0) {
            sk_merge(m, s, mred[wave], sred[wave]);
            G[grow] = -EPS_F * (m + __logf(s));
        }
        grid.sync();
    }
}

// ---------------------------------------------------------------------------
// S = <h, FO - f_aa> + <hi, GO - g_bb>, f_aa = -eps*la/2, g_bb = -eps*lb/2
// (symmetric softmins are exactly diagonal-dominated at this blur).
// GO == final G. out = exp(-S).
// ---------------------------------------------------------------------------
__global__ __launch_bounds__(1024) void sk_finalize(
    const float* __restrict__ fo, const float* __restrict__ go,
    const float* __restrict__ h, const float* __restrict__ hi,
    const float* __restrict__ lw, float* __restrict__ out)
{
    const int tid = threadIdx.x;
    float acc = 0.f;
    for (int r = tid; r < N_PTS; r += 1024)
        acc += h[r] * (fo[r] + 0.5f * EPS_F * lw[r]);
    for (int j = tid; j < M_PTS; j += 1024)
        acc += hi[j] * (go[j] + 0.5f * EPS_F * lw[N_PTS + j]);
    __shared__ float red[1024];
    red[tid] = acc;
    __syncthreads();
    for (int st = 512; st; st >>= 1) {
        if (tid < st) red[tid] += red[tid + st];
        __syncthreads();
    }
    if (tid == 0) out[0] = expf(-red[0]);
}

// ---------------------------------------------------------------------------
extern "C" void kernel_launch(void* const* d_in, const int* in_sizes, int n_in,
                              void* d_out, int out_size, void* d_ws, size_t ws_size,
                              hipStream_t stream)
{
    const float* dpts = (const float*)d_in[0];   // [N, D]
    const float* spts = (const float*)d_in[1];   // [M, D]
    const float* h    = (const float*)d_in[2];   // [N]
    const float* hiw  = (const float*)d_in[3];   // [M]
    const float* W    = (const float*)d_in[4];   // [D, D]
    float* out = (float*)d_out;

    // workspace layout; ~96 MB total
    float* X  = (float*)d_ws;                         // (N+M) x D fp32
    float* XS = X  + (size_t)(N_PTS + M_PTS) * D_DIM; // N+M
    float* LW = XS + (N_PTS + M_PTS);                 // N+M  (la | lb)
    float* F  = LW + (N_PTS + M_PTS);                 // N
    float* G  = F  + N_PTS;                           // M
    float* FO = G  + M_PTS;                           // N
    unsigned short* Q  = (unsigned short*)(FO + N_PTS);   // N x M u16
    unsigned short* QT = Q + (size_t)N_PTS * M_PTS;       // M x N u16

    sk_init_logs<<<(N_PTS + M_PTS + 255) / 256, 256, 0, stream>>>(h, hiw, LW, G);

    sk_gemm_nt<0><<<dim3(D_DIM / 64, N_PTS / 64), 256, 0, stream>>>(
        dpts, W, X, nullptr, nullptr, nullptr, nullptr, N_PTS, D_DIM);
    sk_gemm_nt<0><<<dim3(D_DIM / 64, M_PTS / 64), 256, 0, stream>>>(
        spts, W, X + (size_t)N_PTS * D_DIM, nullptr, nullptr, nullptr, nullptr,
        M_PTS, D_DIM);

    sk_row_norms<<<(N_PTS + M_PTS) / 4, 256, 0, stream>>>(X, XS);

    sk_gemm_nt<1><<<dim3(M_PTS / 64, N_PTS / 64), 256, 0, stream>>>(
        X, X + (size_t)N_PTS * D_DIM, nullptr, Q, QT, XS, XS + N_PTS,
        N_PTS, M_PTS);

    {
        void* args[] = { (void*)&Q, (void*)&QT, (void*)&LW,
                         (void*)&F, (void*)&G, (void*)&FO };
        hipLaunchCooperativeKernel(sk_sinkhorn_coop, dim3(256), dim3(1024),
                                   args, 0, stream);
    }

    sk_finalize<<<1, 1024, 0, stream>>>(FO, G, h, hiw, LW, out);
}

// Round 3
// 1349.285 us; speedup vs baseline: 3.6452x; 3.6452x over previous
//
#include <hip/hip_runtime.h>
#include <math.h>

#define N_PTS 8192
#define M_PTS 2048
#define D_DIM 768
#define EPS_F 0.0025f
#define INV_EPS_F 400.0f
#define SINK_ITERS 50
#define QSCALE_F 12800.0f       // INV_EPS * 32
#define DQ_F (1.0f / 32.0f)     // dequant into exponent units
#define F_BLOCKS (N_PTS / 4)    // 2048 blocks in each F softmin dispatch

typedef __attribute__((ext_vector_type(8))) short short8;
typedef __attribute__((ext_vector_type(4))) float f32x4;

// ---------------------------------------------------------------------------
// init: la | lb into LW, g = 0, control block (conv flag + per-iter counters) = 0
// ---------------------------------------------------------------------------
__global__ __launch_bounds__(256) void sk_init(
    const float* __restrict__ h, const float* __restrict__ hi,
    float* __restrict__ lw, float* __restrict__ g, int* __restrict__ ctrl)
{
    const int t = blockIdx.x * 256 + threadIdx.x;
    if (t < N_PTS)               lw[t] = logf(h[t]);
    else if (t < N_PTS + M_PTS)  lw[t] = logf(hi[t - N_PTS]);
    if (t < M_PTS)               g[t] = 0.f;
    if (t < 64)                  ctrl[t] = 0;   // ctrl[0]=conv, ctrl[1+it]=unchanged count
}

// ---------------------------------------------------------------------------
// fp32 NT-GEMM for the transforms: O[r,s] = dot(A[r,:], B[s,:]) (validated R1)
// ---------------------------------------------------------------------------
__global__ __launch_bounds__(256) void sk_gemm_nt(
    const float* __restrict__ A, const float* __restrict__ B,
    float* __restrict__ O, const int S)
{
    __shared__ float As[16][68];
    __shared__ float Bs[16][68];
    const int tid  = threadIdx.x;
    const int ty   = tid >> 4;
    const int tx   = tid & 15;
    const int row0 = blockIdx.y * 64;
    const int col0 = blockIdx.x * 64;
    const int lrow = tid >> 2;
    const int lk4  = (tid & 3) << 2;
    const float* Ap = A + (size_t)(row0 + lrow) * D_DIM + lk4;
    const float* Bp = B + (size_t)(col0 + lrow) * D_DIM + lk4;
    float acc[4][4] = {};

    for (int k0 = 0; k0 < D_DIM; k0 += 16) {
        const float4 av = *(const float4*)(Ap + k0);
        const float4 bv = *(const float4*)(Bp + k0);
        __syncthreads();
        As[lk4 + 0][lrow] = av.x; As[lk4 + 1][lrow] = av.y;
        As[lk4 + 2][lrow] = av.z; As[lk4 + 3][lrow] = av.w;
        Bs[lk4 + 0][lrow] = bv.x; Bs[lk4 + 1][lrow] = bv.y;
        Bs[lk4 + 2][lrow] = bv.z; Bs[lk4 + 3][lrow] = bv.w;
        __syncthreads();
        #pragma unroll
        for (int kk = 0; kk < 16; ++kk) {
            const float a0 = As[kk][ty * 4 + 0], a1 = As[kk][ty * 4 + 1],
                        a2 = As[kk][ty * 4 + 2], a3 = As[kk][ty * 4 + 3];
            const float b0 = Bs[kk][tx * 4 + 0], b1 = Bs[kk][tx * 4 + 1],
                        b2 = Bs[kk][tx * 4 + 2], b3 = Bs[kk][tx * 4 + 3];
            acc[0][0] = fmaf(a0, b0, acc[0][0]); acc[0][1] = fmaf(a0, b1, acc[0][1]);
            acc[0][2] = fmaf(a0, b2, acc[0][2]); acc[0][3] = fmaf(a0, b3, acc[0][3]);
            acc[1][0] = fmaf(a1, b0, acc[1][0]); acc[1][1] = fmaf(a1, b1, acc[1][1]);
            acc[1][2] = fmaf(a1, b2, acc[1][2]); acc[1][3] = fmaf(a1, b3, acc[1][3]);
            acc[2][0] = fmaf(a2, b0, acc[2][0]); acc[2][1] = fmaf(a2, b1, acc[2][1]);
            acc[2][2] = fmaf(a2, b2, acc[2][2]); acc[2][3] = fmaf(a2, b3, acc[2][3]);
            acc[3][0] = fmaf(a3, b0, acc[3][0]); acc[3][1] = fmaf(a3, b1, acc[3][1]);
            acc[3][2] = fmaf(a3, b2, acc[3][2]); acc[3][3] = fmaf(a3, b3, acc[3][3]);
        }
    }
    #pragma unroll
    for (int i = 0; i < 4; ++i) {
        const float4 v = make_float4(acc[i][0], acc[i][1], acc[i][2], acc[i][3]);
        *(float4*)(O + (size_t)(row0 + ty * 4 + i) * S + col0 + tx * 4) = v;
    }
}

// ---------------------------------------------------------------------------
// xs[r] = 0.5 * ||X[r,:]||^2 (fp32, exact)
// ---------------------------------------------------------------------------
__global__ __launch_bounds__(256) void sk_row_norms(
    const float* __restrict__ X, float* __restrict__ XS)
{
    const int row  = blockIdx.x * 4 + (threadIdx.x >> 6);
    const int lane = threadIdx.x & 63;
    const float* p = X + (size_t)row * D_DIM;
    float s = 0.f;
    #pragma unroll
    for (int k = lane; k < D_DIM; k += 64) { const float v = p[k]; s = fmaf(v, v, s); }
    #pragma unroll
    for (int off = 32; off; off >>= 1) s += __shfl_xor(s, off, 64);
    if (lane == 0) XS[row] = 0.5f * s;
}

// ---------------------------------------------------------------------------
// fp32 -> bf16 (RNE) cast, float4 at a time
// ---------------------------------------------------------------------------
__device__ __forceinline__ unsigned short sk_f2bf(float f)
{
    const unsigned u = __float_as_uint(f);
    return (unsigned short)((u + 0x7fffu + ((u >> 16) & 1u)) >> 16);
}

__global__ __launch_bounds__(256) void sk_cast_bf16(
    const float* __restrict__ X, unsigned short* __restrict__ Xb)
{
    const int t = blockIdx.x * 256 + threadIdx.x;
    const float4 v = ((const float4*)X)[t];
    ushort4 o;
    o.x = sk_f2bf(v.x); o.y = sk_f2bf(v.y); o.z = sk_f2bf(v.z); o.w = sk_f2bf(v.w);
    ((ushort4*)Xb)[t] = o;
}

// ---------------------------------------------------------------------------
// MFMA bf16 cost GEMM + quant epilogue.
// 128x128 tile, 256 thr (4 waves, each 64x64 = 4x4 MFMA 16x16x32 tiles).
// Fragment layouts (m91/m120-verified): A[m=lane&15][k=quad*8+j],
// B[n=lane&15][k=quad*8+j], D[row=quad*4+reg][col=lane&15].
// Q[gm,gn] = sat16(relu(xs[gm]+ys[gn]-dot)*12800); QT = transpose.
// ---------------------------------------------------------------------------
__global__ __launch_bounds__(256) void sk_cost_mfma(
    const unsigned short* __restrict__ Xb, const unsigned short* __restrict__ Yb,
    const float* __restrict__ xs, const float* __restrict__ ys,
    unsigned short* __restrict__ Q, unsigned short* __restrict__ QT)
{
    constexpr int LS = 40;  // LDS row stride in halfs (32 + 8 pad)
    __shared__ unsigned short As[128 * LS];
    __shared__ unsigned short Bs[128 * LS];
    const int tid  = threadIdx.x;
    const int wave = tid >> 6, lane = tid & 63;
    const int quad = lane >> 4, l16 = lane & 15;
    const int row0 = blockIdx.y * 128, col0 = blockIdx.x * 128;
    const int wr = (wave >> 1) * 64, wc = (wave & 1) * 64;

    const int sr = tid >> 2;         // 0..63
    const int sk = (tid & 3) * 8;    // 0,8,16,24
    const unsigned short* Xp  = Xb + (size_t)(row0 + sr) * D_DIM + sk;
    const unsigned short* Xp2 = Xp + (size_t)64 * D_DIM;
    const unsigned short* Yp  = Yb + (size_t)(col0 + sr) * D_DIM + sk;
    const unsigned short* Yp2 = Yp + (size_t)64 * D_DIM;

    f32x4 acc[4][4] = {};

    for (int k0 = 0; k0 < D_DIM; k0 += 32) {
        const short8 a0 = *(const short8*)(Xp + k0);
        const short8 a1 = *(const short8*)(Xp2 + k0);
        const short8 b0 = *(const short8*)(Yp + k0);
        const short8 b1 = *(const short8*)(Yp2 + k0);
        __syncthreads();
        *(short8*)(As + sr * LS + sk)        = a0;
        *(short8*)(As + (sr + 64) * LS + sk) = a1;
        *(short8*)(Bs + sr * LS + sk)        = b0;
        *(short8*)(Bs + (sr + 64) * LS + sk) = b1;
        __syncthreads();
        short8 af[4], bfr[4];
        #pragma unroll
        for (int i = 0; i < 4; ++i) {
            af[i]  = *(const short8*)(As + (wr + i * 16 + l16) * LS + quad * 8);
            bfr[i] = *(const short8*)(Bs + (wc + i * 16 + l16) * LS + quad * 8);
        }
        #pragma unroll
        for (int i = 0; i < 4; ++i)
            #pragma unroll
            for (int j = 0; j < 4; ++j)
                acc[i][j] = __builtin_amdgcn_mfma_f32_16x16x32_bf16(
                    af[i], bfr[j], acc[i][j], 0, 0, 0);
    }

    const int gm0 = row0 + wr + quad * 4;
    const int gn0 = col0 + wc + l16;
    #pragma unroll
    for (int i = 0; i < 4; ++i) {
        float xsv[4];
        #pragma unroll
        for (int r = 0; r < 4; ++r) xsv[r] = xs[gm0 + i * 16 + r];
        #pragma unroll
        for (int j = 0; j < 4; ++j) {
            const int gn = gn0 + j * 16;
            const float ysv = ys[gn];
            unsigned short qv[4];
            #pragma unroll
            for (int r = 0; r < 4; ++r) {
                const float c = fmaxf(xsv[r] + ysv - acc[i][j][r], 0.f);
                qv[r] = (unsigned short)fminf(fmaf(c, QSCALE_F, 0.5f), 65535.f);
            }
            #pragma unroll
            for (int r = 0; r < 4; ++r)
                Q[(size_t)(gm0 + i * 16 + r) * M_PTS + gn] = qv[r];
            *(ushort4*)(QT + (size_t)gn * N_PTS + gm0 + i * 16) =
                make_ushort4(qv[0], qv[1], qv[2], qv[3]);
        }
    }
}

// ---------------------------------------------------------------------------
// softmin helpers
// ---------------------------------------------------------------------------
__device__ __forceinline__ void sk_unpack8(
    const uint4 v, const float4 h0, const float4 h1, float* z)
{
    z[0] = fmaf((float)(v.x & 0xffffu), -DQ_F, h0.x);
    z[1] = fmaf((float)(v.x >> 16),     -DQ_F, h0.y);
    z[2] = fmaf((float)(v.y & 0xffffu), -DQ_F, h0.z);
    z[3] = fmaf((float)(v.y >> 16),     -DQ_F, h0.w);
    z[4] = fmaf((float)(v.z & 0xffffu), -DQ_F, h1.x);
    z[5] = fmaf((float)(v.z >> 16),     -DQ_F, h1.y);
    z[6] = fmaf((float)(v.w & 0xffffu), -DQ_F, h1.z);
    z[7] = fmaf((float)(v.w >> 16),     -DQ_F, h1.w);
}

__device__ __forceinline__ void sk_merge(float& m, float& s, float mc, float sc)
{
    const float nm = fmaxf(m, mc);
    s = s * __expf(m - nm) + sc * __expf(mc - nm);
    m = nm;
}

// ---------------------------------------------------------------------------
// F softmin: F[i] = -eps*LSE_j( lb[j]+G[j]/eps - Q[i,j]*DQ ). 4 rows/block.
// Exact early-exit: skip if converged; count unchanged blocks per iteration.
// ---------------------------------------------------------------------------
template<bool FINAL>
__global__ __launch_bounds__(256) void sk_smF(
    const unsigned short* __restrict__ Q, const float* __restrict__ lb,
    const float* __restrict__ G, float* __restrict__ Fd,
    int* __restrict__ ctrl, const int it)
{
    if (!FINAL && ctrl[0]) return;
    __shared__ __align__(16) float hb[M_PTS];
    __shared__ int blkchg;
    const int tid = threadIdx.x;
    if (tid == 0) blkchg = 0;
    for (int j = tid; j < M_PTS; j += 256)
        hb[j] = fmaf(G[j], INV_EPS_F, lb[j]);
    __syncthreads();

    const int lane = tid & 63;
    const int row  = blockIdx.x * 4 + (tid >> 6);
    const uint4* qp = (const uint4*)(Q + (size_t)row * M_PTS);
    float z[32];
    #pragma unroll
    for (int ld = 0; ld < 4; ++ld) {
        const int idx = ld * 64 + lane;
        const uint4 v = qp[idx];
        const float4 h0 = *(const float4*)&hb[idx * 8];
        const float4 h1 = *(const float4*)&hb[idx * 8 + 4];
        sk_unpack8(v, h0, h1, &z[ld * 8]);
    }
    float m = z[0];
    #pragma unroll
    for (int k = 1; k < 32; ++k) m = fmaxf(m, z[k]);
    float s = 0.f;
    #pragma unroll
    for (int k = 0; k < 32; ++k) s += __expf(z[k] - m);
    #pragma unroll
    for (int off = 1; off < 64; off <<= 1) {
        const float m2 = __shfl_xor(m, off, 64);
        const float s2 = __shfl_xor(s, off, 64);
        sk_merge(m, s, m2, s2);
    }
    if (lane == 0) {
        const float res = -EPS_F * (m + __logf(s));
        if (FINAL) {
            Fd[row] = res;
        } else {
            if (__float_as_uint(res) != __float_as_uint(Fd[row])) blkchg = 1;
            Fd[row] = res;
        }
    }
    if (!FINAL) {
        __syncthreads();
        if (tid == 0 && !blkchg) atomicAdd(&ctrl[1 + it], 1);
    }
}

// ---------------------------------------------------------------------------
// G softmin: G[j] = -eps*LSE_i( la[i]+F[i]/eps - QT[j,i]*DQ ). 4 rows/block.
// If the preceding F pass was bitwise-unchanged, the fixed point is reached:
// set conv and return (G already holds the identical value).
// ---------------------------------------------------------------------------
__global__ __launch_bounds__(256) void sk_smG(
    const unsigned short* __restrict__ QT, const float* __restrict__ la,
    const float* __restrict__ F, float* __restrict__ G,
    int* __restrict__ ctrl, const int it)
{
    if (ctrl[0]) return;
    if (ctrl[1 + it] == F_BLOCKS) { ctrl[0] = 1; return; }
    __shared__ __align__(16) float hb[N_PTS];   // 32 KB
    const int tid = threadIdx.x;
    for (int j = tid; j < N_PTS; j += 256)
        hb[j] = fmaf(F[j], INV_EPS_F, la[j]);
    __syncthreads();

    const int lane = tid & 63;
    const int row  = blockIdx.x * 4 + (tid >> 6);
    const uint4* qp = (const uint4*)(QT + (size_t)row * N_PTS);
    float m = -INFINITY, s = 0.f;
    #pragma unroll
    for (int ch = 0; ch < 4; ++ch) {
        float z[32];
        #pragma unroll
        for (int ld = 0; ld < 4; ++ld) {
            const int idx = ch * 256 + ld * 64 + lane;
            const uint4 v = qp[idx];
            const float4 h0 = *(const float4*)&hb[idx * 8];
            const float4 h1 = *(const float4*)&hb[idx * 8 + 4];
            sk_unpack8(v, h0, h1, &z[ld * 8]);
        }
        float mc = z[0];
        #pragma unroll
        for (int k = 1; k < 32; ++k) mc = fmaxf(mc, z[k]);
        float sc = 0.f;
        #pragma unroll
        for (int k = 0; k < 32; ++k) sc += __expf(z[k] - mc);
        sk_merge(m, s, mc, sc);
    }
    #pragma unroll
    for (int off = 1; off < 64; off <<= 1) {
        const float m2 = __shfl_xor(m, off, 64);
        const float s2 = __shfl_xor(s, off, 64);
        sk_merge(m, s, m2, s2);
    }
    if (lane == 0) G[row] = -EPS_F * (m + __logf(s));
}

// ---------------------------------------------------------------------------
// S = <h, FO + eps*la/2> + <hi, G + eps*lb/2>; out = exp(-S)
// (symmetric debias potentials are analytically -eps*log(w)/2 at this blur)
// ---------------------------------------------------------------------------
__global__ __launch_bounds__(1024) void sk_finalize(
    const float* __restrict__ fo, const float* __restrict__ go,
    const float* __restrict__ h, const float* __restrict__ hi,
    const float* __restrict__ lw, float* __restrict__ out)
{
    const int tid = threadIdx.x;
    float acc = 0.f;
    for (int r = tid; r < N_PTS; r += 1024)
        acc += h[r] * (fo[r] + 0.5f * EPS_F * lw[r]);
    for (int j = tid; j < M_PTS; j += 1024)
        acc += hi[j] * (go[j] + 0.5f * EPS_F * lw[N_PTS + j]);
    __shared__ float red[1024];
    red[tid] = acc;
    __syncthreads();
    for (int st = 512; st; st >>= 1) {
        if (tid < st) red[tid] += red[tid + st];
        __syncthreads();
    }
    if (tid == 0) out[0] = expf(-red[0]);
}

// ---------------------------------------------------------------------------
extern "C" void kernel_launch(void* const* d_in, const int* in_sizes, int n_in,
                              void* d_out, int out_size, void* d_ws, size_t ws_size,
                              hipStream_t stream)
{
    const float* dpts = (const float*)d_in[0];   // [N, D]
    const float* spts = (const float*)d_in[1];   // [M, D]
    const float* h    = (const float*)d_in[2];   // [N]
    const float* hiw  = (const float*)d_in[3];   // [M]
    const float* W    = (const float*)d_in[4];   // [D, D]
    float* out = (float*)d_out;

    // workspace layout (~114 MB)
    float* X  = (float*)d_ws;                         // (N+M) x D fp32
    float* XS = X  + (size_t)(N_PTS + M_PTS) * D_DIM; // N+M
    float* LW = XS + (N_PTS + M_PTS);                 // N+M (la | lb)
    float* F  = LW + (N_PTS + M_PTS);                 // N
    float* G  = F  + N_PTS;                           // M
    float* FO = G  + M_PTS;                           // N
    int*   CT = (int*)(FO + N_PTS);                   // 64 ints control
    unsigned short* Xb = (unsigned short*)(CT + 64);  // (N+M) x D bf16
    unsigned short* Q  = Xb + (size_t)(N_PTS + M_PTS) * D_DIM; // N x M u16
    unsigned short* QT = Q  + (size_t)N_PTS * M_PTS;            // M x N u16

    sk_init<<<(N_PTS + M_PTS + 255) / 256, 256, 0, stream>>>(h, hiw, LW, G, CT);

    sk_gemm_nt<<<dim3(D_DIM / 64, N_PTS / 64), 256, 0, stream>>>(dpts, W, X, D_DIM);
    sk_gemm_nt<<<dim3(D_DIM / 64, M_PTS / 64), 256, 0, stream>>>(
        spts, W, X + (size_t)N_PTS * D_DIM, D_DIM);

    sk_row_norms<<<(N_PTS + M_PTS) / 4, 256, 0, stream>>>(X, XS);
    sk_cast_bf16<<<((N_PTS + M_PTS) * D_DIM / 4) / 256, 256, 0, stream>>>(X, Xb);

    sk_cost_mfma<<<dim3(M_PTS / 128, N_PTS / 128), 256, 0, stream>>>(
        Xb, Xb + (size_t)N_PTS * D_DIM, XS, XS + N_PTS, Q, QT);

    for (int it = 0; it < SINK_ITERS; ++it) {
        sk_smF<false><<<N_PTS / 4, 256, 0, stream>>>(Q,  LW + N_PTS, G, F, CT, it);
        sk_smG       <<<M_PTS / 4, 256, 0, stream>>>(QT, LW,         F, G, CT, it);
    }
    sk_smF<true><<<N_PTS / 4, 256, 0, stream>>>(Q, LW + N_PTS, G, FO, CT, 0);

    sk_finalize<<<1, 1024, 0, stream>>>(FO, G, h, hiw, LW, out);
}

// Round 4
// 1247.317 us; speedup vs baseline: 3.9432x; 1.0817x over previous
//
#include <hip/hip_runtime.h>
#include <math.h>

#define N_PTS 8192
#define M_PTS 2048
#define NM_PTS 10240
#define D_DIM 768
#define EPS_F 0.0025f
#define INV_EPS_F 400.0f
#define SINK_ITERS 50
#define QSCALE_F 12800.0f     // u16 units: (C/eps)*32  (step 1/32 nat)
#define R8_STEP_F 0.375f      // u8 residual step in nats = 12 u16 units
#define U16_TO_NAT 0.03125f

typedef __attribute__((ext_vector_type(8))) short short8;
typedef __attribute__((ext_vector_type(4))) float f32x4;

// ---------------------------------------------------------------------------
__device__ __forceinline__ unsigned short sk_f2bf(float f)
{
    const unsigned u = __float_as_uint(f);
    return (unsigned short)((u + 0x7fffu + ((u >> 16) & 1u)) >> 16);
}

__device__ __forceinline__ void sk_merge(float& m, float& s, float mc, float sc)
{
    const float nm = fmaxf(m, mc);
    s = s * __expf(m - nm) + sc * __expf(mc - nm);
    m = nm;
}

// unpack 4 bytes of w into z[o..o+3] = hbr - byte*0.375
__device__ __forceinline__ void sk_z4(unsigned int w, const float* hbr, int o, float* z)
{
    z[o + 0] = fmaf((float)(w & 0xffu),         -R8_STEP_F, hbr[o + 0]);
    z[o + 1] = fmaf((float)((w >> 8) & 0xffu),  -R8_STEP_F, hbr[o + 1]);
    z[o + 2] = fmaf((float)((w >> 16) & 0xffu), -R8_STEP_F, hbr[o + 2]);
    z[o + 3] = fmaf((float)(w >> 24),           -R8_STEP_F, hbr[o + 3]);
}

// ---------------------------------------------------------------------------
// init: LW = (log h | log hi), hbF = log hi (g=0), R32 = INT_MAX
// ---------------------------------------------------------------------------
__global__ __launch_bounds__(256) void sk_init(
    const float* __restrict__ h, const float* __restrict__ hi,
    float* __restrict__ lw, float* __restrict__ hbF, int* __restrict__ r32)
{
    const int t = blockIdx.x * 256 + threadIdx.x;
    if (t < N_PTS) { lw[t] = logf(h[t]); r32[t] = 0x7fffffff; }
    else if (t < NM_PTS) {
        const float v = logf(hi[t - N_PTS]);
        lw[t] = v; hbF[t - N_PTS] = v;
    }
}

// ---------------------------------------------------------------------------
// fp32 -> bf16 cast (float4 granular)
// ---------------------------------------------------------------------------
__global__ __launch_bounds__(256) void sk_cast(
    const float* __restrict__ src, unsigned short* __restrict__ dst)
{
    const int t = blockIdx.x * 256 + threadIdx.x;
    const float4 v = ((const float4*)src)[t];
    ushort4 o;
    o.x = sk_f2bf(v.x); o.y = sk_f2bf(v.y); o.z = sk_f2bf(v.z); o.w = sk_f2bf(v.w);
    ((ushort4*)dst)[t] = o;
}

// ---------------------------------------------------------------------------
// MFMA bf16 NT-GEMM, 128x128 tile, 256 thr.
// MODE 0 (transform): Xb[gm,gn] = bf16(dot) via LDS-transpose epilogue.
// MODE 1 (cost): q = sat_u16(relu(xs+ys-dot)*12800); writes column-packed
//                QTu16[gn,gm] + per-row atomicMin into R32.
// Fragment layouts (m91-verified): A[m=lane&15][k=quad*8+j], D[row=quad*4+r][col=lane&15].
// ---------------------------------------------------------------------------
template<int MODE>
__global__ __launch_bounds__(256) void sk_mfma(
    const unsigned short* __restrict__ A, const unsigned short* __restrict__ B,
    unsigned short* __restrict__ Xb,
    unsigned short* __restrict__ QT, int* __restrict__ R32,
    const float* __restrict__ xs, const float* __restrict__ ys)
{
    constexpr int LS = 40;  // LDS row stride (32 + 8 pad) halfs
    __shared__ unsigned short As[128 * LS];
    __shared__ unsigned short Bs[128 * LS];
    __shared__ int rmin[128];
    const int tid  = threadIdx.x;
    const int wave = tid >> 6, lane = tid & 63;
    const int quad = lane >> 4, l16 = lane & 15;
    const int row0 = blockIdx.y * 128, col0 = blockIdx.x * 128;
    const int wr = (wave >> 1) * 64, wc = (wave & 1) * 64;
    if (MODE == 1 && tid < 128) rmin[tid] = 0x7fffffff;

    const int sr = tid >> 2;
    const int sk = (tid & 3) * 8;
    const unsigned short* Ap  = A + (size_t)(row0 + sr) * D_DIM + sk;
    const unsigned short* Ap2 = Ap + (size_t)64 * D_DIM;
    const unsigned short* Bp  = B + (size_t)(col0 + sr) * D_DIM + sk;
    const unsigned short* Bp2 = Bp + (size_t)64 * D_DIM;

    f32x4 acc[4][4] = {};

    for (int k0 = 0; k0 < D_DIM; k0 += 32) {
        const short8 a0 = *(const short8*)(Ap + k0);
        const short8 a1 = *(const short8*)(Ap2 + k0);
        const short8 b0 = *(const short8*)(Bp + k0);
        const short8 b1 = *(const short8*)(Bp2 + k0);
        __syncthreads();
        *(short8*)(As + sr * LS + sk)        = a0;
        *(short8*)(As + (sr + 64) * LS + sk) = a1;
        *(short8*)(Bs + sr * LS + sk)        = b0;
        *(short8*)(Bs + (sr + 64) * LS + sk) = b1;
        __syncthreads();
        short8 af[4], bfr[4];
        #pragma unroll
        for (int i = 0; i < 4; ++i) {
            af[i]  = *(const short8*)(As + (wr + i * 16 + l16) * LS + quad * 8);
            bfr[i] = *(const short8*)(Bs + (wc + i * 16 + l16) * LS + quad * 8);
        }
        #pragma unroll
        for (int i = 0; i < 4; ++i)
            #pragma unroll
            for (int j = 0; j < 4; ++j)
                acc[i][j] = __builtin_amdgcn_mfma_f32_16x16x32_bf16(
                    af[i], bfr[j], acc[i][j], 0, 0, 0);
    }

    if (MODE == 0) {
        // LDS-transpose epilogue: slab of 2x16 rows x 128 cols bf16 in As.
        unsigned short* sl = As;
        const int sgrp = wr >> 6;
        const int osg = tid >> 7, orow = (tid >> 3) & 15, oc16 = (tid & 7) * 16;
        #pragma unroll
        for (int i = 0; i < 4; ++i) {
            __syncthreads();
            #pragma unroll
            for (int j = 0; j < 4; ++j)
                #pragma unroll
                for (int r = 0; r < 4; ++r)
                    sl[sgrp * 2176 + (quad * 4 + r) * 136 + wc + j * 16 + l16] =
                        sk_f2bf(acc[i][j][r]);
            __syncthreads();
            const unsigned short* src = sl + osg * 2176 + orow * 136 + oc16;
            const short8 v0 = *(const short8*)src;
            const short8 v1 = *(const short8*)(src + 8);
            unsigned short* dst = Xb +
                (size_t)(row0 + osg * 64 + i * 16 + orow) * D_DIM + col0 + oc16;
            *(short8*)dst = v0;
            *(short8*)(dst + 8) = v1;
        }
    } else {
        const int gm0 = row0 + wr + quad * 4;
        const int gn0 = col0 + wc + l16;
        #pragma unroll
        for (int i = 0; i < 4; ++i) {
            float xv[4];
            #pragma unroll
            for (int r = 0; r < 4; ++r) xv[r] = xs[gm0 + i * 16 + r];
            int qmn[4] = {0x7fffffff, 0x7fffffff, 0x7fffffff, 0x7fffffff};
            #pragma unroll
            for (int j = 0; j < 4; ++j) {
                const int gn = gn0 + j * 16;
                const float ysv = ys[gn];
                int iq[4];
                #pragma unroll
                for (int r = 0; r < 4; ++r) {
                    const float c = fmaxf(xv[r] + ysv - acc[i][j][r], 0.f);
                    iq[r] = (int)fminf(fmaf(c, QSCALE_F, 0.5f), 65535.f);
                    qmn[r] = min(qmn[r], iq[r]);
                }
                *(ushort4*)(QT + (size_t)gn * N_PTS + gm0 + i * 16) =
                    make_ushort4((unsigned short)iq[0], (unsigned short)iq[1],
                                 (unsigned short)iq[2], (unsigned short)iq[3]);
            }
            #pragma unroll
            for (int r = 0; r < 4; ++r)
                atomicMin(&rmin[wr + i * 16 + quad * 4 + r], qmn[r]);
        }
        __syncthreads();
        if (tid < 128) atomicMin(&R32[row0 + tid], rmin[tid]);
    }
}

// ---------------------------------------------------------------------------
// xs[r] = 0.5*||Xb[r,:]||^2 from bf16 (consistent with cost cross-term)
// ---------------------------------------------------------------------------
__global__ __launch_bounds__(256) void sk_row_norms(
    const unsigned short* __restrict__ Xb, float* __restrict__ XS)
{
    const int row  = blockIdx.x * 4 + (threadIdx.x >> 6);
    const int lane = threadIdx.x & 63;
    const unsigned int* p = (const unsigned int*)(Xb + (size_t)row * D_DIM);
    float s = 0.f;
    #pragma unroll
    for (int k = 0; k < 6; ++k) {
        const unsigned int u = p[lane + k * 64];
        const float f0 = __uint_as_float(u << 16);
        const float f1 = __uint_as_float(u & 0xffff0000u);
        s = fmaf(f0, f0, s); s = fmaf(f1, f1, s);
    }
    #pragma unroll
    for (int off = 32; off; off >>= 1) s += __shfl_xor(s, off, 64);
    if (lane == 0) XS[row] = 0.5f * s;
}

// ---------------------------------------------------------------------------
// Transpose+quant: QTu16 [2048 x 8192] -> Q8 row-major [8192 x 2048] u8
// residuals w.r.t. row-min R32[i]. 64x64 tiles via LDS.
// ---------------------------------------------------------------------------
__global__ __launch_bounds__(256) void sk_transq(
    const unsigned short* __restrict__ QT, const int* __restrict__ R32,
    unsigned char* __restrict__ Q8)
{
    __shared__ unsigned short tile[64][72];
    const int tid = threadIdx.x;
    const int J0 = blockIdx.x * 64;   // j (cols of Q8)
    const int I0 = blockIdx.y * 64;   // i (rows of Q8)
    {
        const int tj = tid >> 2, ti = (tid & 3) * 16;
        const uint4* src = (const uint4*)(QT + (size_t)(J0 + tj) * N_PTS + I0 + ti);
        const uint4 a = src[0], b = src[1];
        *(uint4*)&tile[tj][ti] = a;
        *(uint4*)&tile[tj][ti + 8] = b;
    }
    __syncthreads();
    const int li = tid >> 2, lj = (tid & 3) * 16;
    const int R = R32[I0 + li];
    unsigned char ob[16];
    #pragma unroll
    for (int k = 0; k < 16; ++k) {
        const int q = (int)tile[lj + k][li];
        ob[k] = (unsigned char)fminf(fmaf((float)(q - R), 1.0f / 12.0f, 0.5f), 255.f);
    }
    *(uint4*)(Q8 + (size_t)(I0 + li) * M_PTS + J0 + lj) = *(const uint4*)ob;
}

// ---------------------------------------------------------------------------
// QTu16 -> QT8 (same layout), residual vs R32[i] (i = position in row)
// ---------------------------------------------------------------------------
__global__ __launch_bounds__(256) void sk_requant_qt(
    const unsigned short* __restrict__ QT, const int* __restrict__ R32,
    unsigned char* __restrict__ QT8)
{
    const size_t base = ((size_t)blockIdx.x * 256 + threadIdx.x) * 16;
    const int i0 = (int)(base & (size_t)(N_PTS - 1));
    const uint4* src = (const uint4*)(QT + base);
    const uint4 a = src[0], b = src[1];
    unsigned int qs[8] = {a.x, a.y, a.z, a.w, b.x, b.y, b.z, b.w};
    const int* rp = R32 + i0;
    unsigned char ob[16];
    #pragma unroll
    for (int k = 0; k < 8; ++k) {
        const int q0 = (int)(qs[k] & 0xffffu), q1 = (int)(qs[k] >> 16);
        ob[2 * k]     = (unsigned char)fminf(fmaf((float)(q0 - rp[2 * k]),     1.0f / 12.0f, 0.5f), 255.f);
        ob[2 * k + 1] = (unsigned char)fminf(fmaf((float)(q1 - rp[2 * k + 1]), 1.0f / 12.0f, 0.5f), 255.f);
    }
    *(uint4*)(QT8 + base) = *(const uint4*)ob;
}

// ---------------------------------------------------------------------------
// F softmin over Q8 rows (2048 cols). 8 rows/block, 512 thr, 1024 blocks.
// hb register-resident: lane L holds hbF[32L..32L+31]. No LDS, no syncs.
// non-final: hbG[i] = la[i] - LSE_res ; final: FO[i] = eps*(R_i - LSE_res)
// ---------------------------------------------------------------------------
template<bool FINAL>
__global__ __launch_bounds__(512) void sk_smF(
    const unsigned char* __restrict__ Q8, const float* __restrict__ hbF,
    const float* __restrict__ LW, const int* __restrict__ R32,
    float* __restrict__ outv)
{
    const int tid = threadIdx.x, wave = tid >> 6, lane = tid & 63;
    float hbr[32];
    const float4* hb4 = (const float4*)hbF;
    #pragma unroll
    for (int t = 0; t < 8; ++t) {
        const float4 v = hb4[lane * 8 + t];
        hbr[t * 4 + 0] = v.x; hbr[t * 4 + 1] = v.y;
        hbr[t * 4 + 2] = v.z; hbr[t * 4 + 3] = v.w;
    }
    const int row = blockIdx.x * 8 + wave;
    const uint4* qp = (const uint4*)(Q8 + (size_t)row * M_PTS);
    const uint4 q0 = qp[lane * 2], q1 = qp[lane * 2 + 1];
    float z[32];
    sk_z4(q0.x, hbr, 0, z);  sk_z4(q0.y, hbr, 4, z);
    sk_z4(q0.z, hbr, 8, z);  sk_z4(q0.w, hbr, 12, z);
    sk_z4(q1.x, hbr, 16, z); sk_z4(q1.y, hbr, 20, z);
    sk_z4(q1.z, hbr, 24, z); sk_z4(q1.w, hbr, 28, z);
    float m = z[0];
    #pragma unroll
    for (int k = 1; k < 32; ++k) m = fmaxf(m, z[k]);
    float s = 0.f;
    #pragma unroll
    for (int k = 0; k < 32; ++k) s += __expf(z[k] - m);
    #pragma unroll
    for (int off = 1; off < 64; off <<= 1) {
        const float m2 = __shfl_xor(m, off, 64);
        const float s2 = __shfl_xor(s, off, 64);
        sk_merge(m, s, m2, s2);
    }
    if (lane == 0) {
        const float lse = m + __logf(s);
        if (FINAL) outv[row] = EPS_F * ((float)R32[row] * U16_TO_NAT - lse);
        else       outv[row] = LW[row] - lse;
    }
}

// ---------------------------------------------------------------------------
// G softmin over QT8 rows (8192 cols). 4 rows/block, 256 thr, 512 blocks.
// 4 segments of 2048; hbG register-resident per segment.
// writes hbF[j] = lb[j] - LSE_res
// ---------------------------------------------------------------------------
__global__ __launch_bounds__(256) void sk_smG(
    const unsigned char* __restrict__ QT8, const float* __restrict__ hbG,
    const float* __restrict__ LW, float* __restrict__ hbF)
{
    const int tid = threadIdx.x, wave = tid >> 6, lane = tid & 63;
    const int row = blockIdx.x * 4 + wave;
    const uint4* qp = (const uint4*)(QT8 + (size_t)row * N_PTS);
    const float4* hb4 = (const float4*)hbG;
    float m = -INFINITY, s = 0.f;
    #pragma unroll
    for (int seg = 0; seg < 4; ++seg) {
        float hbr[32];
        #pragma unroll
        for (int t = 0; t < 8; ++t) {
            const float4 v = hb4[seg * 512 + lane * 8 + t];
            hbr[t * 4 + 0] = v.x; hbr[t * 4 + 1] = v.y;
            hbr[t * 4 + 2] = v.z; hbr[t * 4 + 3] = v.w;
        }
        const uint4 q0 = qp[seg * 128 + lane * 2], q1 = qp[seg * 128 + lane * 2 + 1];
        float z[32];
        sk_z4(q0.x, hbr, 0, z);  sk_z4(q0.y, hbr, 4, z);
        sk_z4(q0.z, hbr, 8, z);  sk_z4(q0.w, hbr, 12, z);
        sk_z4(q1.x, hbr, 16, z); sk_z4(q1.y, hbr, 20, z);
        sk_z4(q1.z, hbr, 24, z); sk_z4(q1.w, hbr, 28, z);
        float mc = z[0];
        #pragma unroll
        for (int k = 1; k < 32; ++k) mc = fmaxf(mc, z[k]);
        float sc = 0.f;
        #pragma unroll
        for (int k = 0; k < 32; ++k) sc += __expf(z[k] - mc);
        sk_merge(m, s, mc, sc);
    }
    #pragma unroll
    for (int off = 1; off < 64; off <<= 1) {
        const float m2 = __shfl_xor(m, off, 64);
        const float s2 = __shfl_xor(s, off, 64);
        sk_merge(m, s, m2, s2);
    }
    if (lane == 0) hbF[row] = LW[N_PTS + row] - (m + __logf(s));
}

// ---------------------------------------------------------------------------
// S = <h, FO + eps*la/2> + <hi, eps*(hbF - lb/2)>; out = exp(-S)
// (G_j = eps*(hbF_j - lb_j); debias potentials analytic: -eps*log(w)/2)
// ---------------------------------------------------------------------------
__global__ __launch_bounds__(1024) void sk_finalize(
    const float* __restrict__ fo, const float* __restrict__ hbF,
    const float* __restrict__ h, const float* __restrict__ hi,
    const float* __restrict__ lw, float* __restrict__ out)
{
    const int tid = threadIdx.x;
    float acc = 0.f;
    for (int r = tid; r < N_PTS; r += 1024)
        acc += h[r] * (fo[r] + 0.5f * EPS_F * lw[r]);
    for (int j = tid; j < M_PTS; j += 1024)
        acc += hi[j] * EPS_F * (hbF[j] - 0.5f * lw[N_PTS + j]);
    __shared__ float red[1024];
    red[tid] = acc;
    __syncthreads();
    for (int st = 512; st; st >>= 1) {
        if (tid < st) red[tid] += red[tid + st];
        __syncthreads();
    }
    if (tid == 0) out[0] = expf(-red[0]);
}

// ---------------------------------------------------------------------------
extern "C" void kernel_launch(void* const* d_in, const int* in_sizes, int n_in,
                              void* d_out, int out_size, void* d_ws, size_t ws_size,
                              hipStream_t stream)
{
    const float* dpts = (const float*)d_in[0];   // [N, D]
    const float* spts = (const float*)d_in[1];   // [M, D]
    const float* h    = (const float*)d_in[2];   // [N]
    const float* hiw  = (const float*)d_in[3];   // [M]
    const float* W    = (const float*)d_in[4];   // [D, D]
    float* out = (float*)d_out;

    // workspace (~100 MB)
    float* XS  = (float*)d_ws;                        // NM
    float* LW  = XS + NM_PTS;                         // NM (la | lb)
    float* HBF = LW + NM_PTS;                         // M
    float* HBG = HBF + M_PTS;                         // N
    float* FO  = HBG + N_PTS;                         // N
    int*   R32 = (int*)(FO + N_PTS);                  // N
    unsigned short* Db = (unsigned short*)(R32 + N_PTS);        // NM x D bf16
    unsigned short* Wb = Db + (size_t)NM_PTS * D_DIM;           // D x D bf16
    unsigned short* Xb = Wb + (size_t)D_DIM * D_DIM;            // NM x D bf16
    unsigned short* QTu = Xb + (size_t)NM_PTS * D_DIM;          // M x N u16
    unsigned char*  Q8  = (unsigned char*)(QTu + (size_t)M_PTS * N_PTS); // N x M u8
    unsigned char*  QT8 = Q8 + (size_t)N_PTS * M_PTS;           // M x N u8

    sk_init<<<NM_PTS / 256, 256, 0, stream>>>(h, hiw, LW, HBF, R32);

    sk_cast<<<(size_t)N_PTS * D_DIM / 1024, 256, 0, stream>>>(dpts, Db);
    sk_cast<<<(size_t)M_PTS * D_DIM / 1024, 256, 0, stream>>>(
        spts, Db + (size_t)N_PTS * D_DIM);
    sk_cast<<<(size_t)D_DIM * D_DIM / 1024, 256, 0, stream>>>(W, Wb);

    // Xb = bf16(Db @ Wb^T)
    sk_mfma<0><<<dim3(D_DIM / 128, NM_PTS / 128), 256, 0, stream>>>(
        Db, Wb, Xb, nullptr, nullptr, nullptr, nullptr);

    sk_row_norms<<<NM_PTS / 4, 256, 0, stream>>>(Xb, XS);

    // QTu16[j,i] = sat16((xs_i + ys_j - x_i.y_j)*12800), R32[i] = row min
    sk_mfma<1><<<dim3(M_PTS / 128, N_PTS / 128), 256, 0, stream>>>(
        Xb, Xb + (size_t)N_PTS * D_DIM, nullptr, QTu, R32, XS, XS + N_PTS);

    sk_transq<<<dim3(M_PTS / 64, N_PTS / 64), 256, 0, stream>>>(QTu, R32, Q8);
    sk_requant_qt<<<(size_t)M_PTS * N_PTS / 4096, 256, 0, stream>>>(QTu, R32, QT8);

    for (int it = 0; it < SINK_ITERS; ++it) {
        sk_smF<false><<<N_PTS / 8, 512, 0, stream>>>(Q8, HBF, LW, R32, HBG);
        sk_smG       <<<M_PTS / 4, 256, 0, stream>>>(QT8, HBG, LW, HBF);
    }
    sk_smF<true><<<N_PTS / 8, 512, 0, stream>>>(Q8, HBF, LW, R32, FO);

    sk_finalize<<<1, 1024, 0, stream>>>(FO, HBF, h, hiw, LW, out);
}

// Round 5
// 880.557 us; speedup vs baseline: 5.5856x; 1.4165x over previous
//
#include <hip/hip_runtime.h>
#include <math.h>

#define N_PTS 8192
#define M_PTS 2048
#define NM_PTS 10240
#define D_DIM 768
#define EPS_F 0.0025f
#define INV_EPS_F 400.0f
#define SINK_ITERS 50
#define QSCALE_F 12800.0f     // u16 units: (C/eps)*32  (step 1/32 nat)
#define R8_STEP_F 0.375f      // u8 residual step in nats = 12 u16 units
#define U16_TO_NAT 0.03125f

typedef __attribute__((ext_vector_type(8))) short short8;
typedef __attribute__((ext_vector_type(4))) float f32x4;

// Layout note (round-5): Q8 / QT8 rows are stored PERMUTED per 2048-col
// segment: byte position p = 32L + 4t + e  (L=0..63, t=0..7, e=0..3) holds
// the residual of logical column c = 256t + 4L + e. Lane L of a wave reads
// bytes [32L..32L+31] (two uint4) and the matching bias floats with
// hb4[64t + lane] -> fully coalesced (round-4 layout made this a 64-line
// gather, ~7 us/dispatch of L1-tag serialization).

// ---------------------------------------------------------------------------
__device__ __forceinline__ unsigned short sk_f2bf(float f)
{
    const unsigned u = __float_as_uint(f);
    return (unsigned short)((u + 0x7fffu + ((u >> 16) & 1u)) >> 16);
}

__device__ __forceinline__ void sk_merge(float& m, float& s, float mc, float sc)
{
    const float nm = fmaxf(m, mc);
    s = s * __expf(m - nm) + sc * __expf(mc - nm);
    m = nm;
}

// unpack 4 bytes of w into z[o..o+3] = hbr - byte*0.375
__device__ __forceinline__ void sk_z4(unsigned int w, const float* hbr, int o, float* z)
{
    z[o + 0] = fmaf((float)(w & 0xffu),         -R8_STEP_F, hbr[o + 0]);
    z[o + 1] = fmaf((float)((w >> 8) & 0xffu),  -R8_STEP_F, hbr[o + 1]);
    z[o + 2] = fmaf((float)((w >> 16) & 0xffu), -R8_STEP_F, hbr[o + 2]);
    z[o + 3] = fmaf((float)(w >> 24),           -R8_STEP_F, hbr[o + 3]);
}

// 32-element LSE chunk from two uint4 + register-resident hbr[32]
__device__ __forceinline__ void sk_lse32(
    const uint4 q0, const uint4 q1, const float* hbr, float& mc, float& sc)
{
    float z[32];
    sk_z4(q0.x, hbr, 0, z);  sk_z4(q0.y, hbr, 4, z);
    sk_z4(q0.z, hbr, 8, z);  sk_z4(q0.w, hbr, 12, z);
    sk_z4(q1.x, hbr, 16, z); sk_z4(q1.y, hbr, 20, z);
    sk_z4(q1.z, hbr, 24, z); sk_z4(q1.w, hbr, 28, z);
    mc = z[0];
    #pragma unroll
    for (int k = 1; k < 32; ++k) mc = fmaxf(mc, z[k]);
    sc = 0.f;
    #pragma unroll
    for (int k = 0; k < 32; ++k) sc += __expf(z[k] - mc);
}

// ---------------------------------------------------------------------------
// init: LW = (log h | log hi), hbF = log hi (g=0), R32 = INT_MAX
// ---------------------------------------------------------------------------
__global__ __launch_bounds__(256) void sk_init(
    const float* __restrict__ h, const float* __restrict__ hi,
    float* __restrict__ lw, float* __restrict__ hbF, int* __restrict__ r32)
{
    const int t = blockIdx.x * 256 + threadIdx.x;
    if (t < N_PTS) { lw[t] = logf(h[t]); r32[t] = 0x7fffffff; }
    else if (t < NM_PTS) {
        const float v = logf(hi[t - N_PTS]);
        lw[t] = v; hbF[t - N_PTS] = v;
    }
}

// ---------------------------------------------------------------------------
__global__ __launch_bounds__(256) void sk_cast(
    const float* __restrict__ src, unsigned short* __restrict__ dst)
{
    const int t = blockIdx.x * 256 + threadIdx.x;
    const float4 v = ((const float4*)src)[t];
    ushort4 o;
    o.x = sk_f2bf(v.x); o.y = sk_f2bf(v.y); o.z = sk_f2bf(v.z); o.w = sk_f2bf(v.w);
    ((ushort4*)dst)[t] = o;
}

// ---------------------------------------------------------------------------
// MFMA bf16 NT-GEMM, 128x128 tile, 256 thr. (r4-validated)
// MODE 0: Xb[gm,gn] = bf16(dot) via LDS-transpose epilogue.
// MODE 1: q = sat_u16(relu(xs+ys-dot)*12800); writes column-packed
//         QTu16[gn,gm] + per-row atomicMin into R32.
// ---------------------------------------------------------------------------
template<int MODE>
__global__ __launch_bounds__(256) void sk_mfma(
    const unsigned short* __restrict__ A, const unsigned short* __restrict__ B,
    unsigned short* __restrict__ Xb,
    unsigned short* __restrict__ QT, int* __restrict__ R32,
    const float* __restrict__ xs, const float* __restrict__ ys)
{
    constexpr int LS = 40;
    __shared__ unsigned short As[128 * LS];
    __shared__ unsigned short Bs[128 * LS];
    __shared__ int rmin[128];
    const int tid  = threadIdx.x;
    const int wave = tid >> 6, lane = tid & 63;
    const int quad = lane >> 4, l16 = lane & 15;
    const int row0 = blockIdx.y * 128, col0 = blockIdx.x * 128;
    const int wr = (wave >> 1) * 64, wc = (wave & 1) * 64;
    if (MODE == 1 && tid < 128) rmin[tid] = 0x7fffffff;

    const int sr = tid >> 2;
    const int sk = (tid & 3) * 8;
    const unsigned short* Ap  = A + (size_t)(row0 + sr) * D_DIM + sk;
    const unsigned short* Ap2 = Ap + (size_t)64 * D_DIM;
    const unsigned short* Bp  = B + (size_t)(col0 + sr) * D_DIM + sk;
    const unsigned short* Bp2 = Bp + (size_t)64 * D_DIM;

    f32x4 acc[4][4] = {};

    for (int k0 = 0; k0 < D_DIM; k0 += 32) {
        const short8 a0 = *(const short8*)(Ap + k0);
        const short8 a1 = *(const short8*)(Ap2 + k0);
        const short8 b0 = *(const short8*)(Bp + k0);
        const short8 b1 = *(const short8*)(Bp2 + k0);
        __syncthreads();
        *(short8*)(As + sr * LS + sk)        = a0;
        *(short8*)(As + (sr + 64) * LS + sk) = a1;
        *(short8*)(Bs + sr * LS + sk)        = b0;
        *(short8*)(Bs + (sr + 64) * LS + sk) = b1;
        __syncthreads();
        short8 af[4], bfr[4];
        #pragma unroll
        for (int i = 0; i < 4; ++i) {
            af[i]  = *(const short8*)(As + (wr + i * 16 + l16) * LS + quad * 8);
            bfr[i] = *(const short8*)(Bs + (wc + i * 16 + l16) * LS + quad * 8);
        }
        #pragma unroll
        for (int i = 0; i < 4; ++i)
            #pragma unroll
            for (int j = 0; j < 4; ++j)
                acc[i][j] = __builtin_amdgcn_mfma_f32_16x16x32_bf16(
                    af[i], bfr[j], acc[i][j], 0, 0, 0);
    }

    if (MODE == 0) {
        unsigned short* sl = As;
        const int sgrp = wr >> 6;
        const int osg = tid >> 7, orow = (tid >> 3) & 15, oc16 = (tid & 7) * 16;
        #pragma unroll
        for (int i = 0; i < 4; ++i) {
            __syncthreads();
            #pragma unroll
            for (int j = 0; j < 4; ++j)
                #pragma unroll
                for (int r = 0; r < 4; ++r)
                    sl[sgrp * 2176 + (quad * 4 + r) * 136 + wc + j * 16 + l16] =
                        sk_f2bf(acc[i][j][r]);
            __syncthreads();
            const unsigned short* src = sl + osg * 2176 + orow * 136 + oc16;
            const short8 v0 = *(const short8*)src;
            const short8 v1 = *(const short8*)(src + 8);
            unsigned short* dst = Xb +
                (size_t)(row0 + osg * 64 + i * 16 + orow) * D_DIM + col0 + oc16;
            *(short8*)dst = v0;
            *(short8*)(dst + 8) = v1;
        }
    } else {
        const int gm0 = row0 + wr + quad * 4;
        const int gn0 = col0 + wc + l16;
        #pragma unroll
        for (int i = 0; i < 4; ++i) {
            float xv[4];
            #pragma unroll
            for (int r = 0; r < 4; ++r) xv[r] = xs[gm0 + i * 16 + r];
            int qmn[4] = {0x7fffffff, 0x7fffffff, 0x7fffffff, 0x7fffffff};
            #pragma unroll
            for (int j = 0; j < 4; ++j) {
                const int gn = gn0 + j * 16;
                const float ysv = ys[gn];
                int iq[4];
                #pragma unroll
                for (int r = 0; r < 4; ++r) {
                    const float c = fmaxf(xv[r] + ysv - acc[i][j][r], 0.f);
                    iq[r] = (int)fminf(fmaf(c, QSCALE_F, 0.5f), 65535.f);
                    qmn[r] = min(qmn[r], iq[r]);
                }
                *(ushort4*)(QT + (size_t)gn * N_PTS + gm0 + i * 16) =
                    make_ushort4((unsigned short)iq[0], (unsigned short)iq[1],
                                 (unsigned short)iq[2], (unsigned short)iq[3]);
            }
            #pragma unroll
            for (int r = 0; r < 4; ++r)
                atomicMin(&rmin[wr + i * 16 + quad * 4 + r], qmn[r]);
        }
        __syncthreads();
        if (tid < 128) atomicMin(&R32[row0 + tid], rmin[tid]);
    }
}

// ---------------------------------------------------------------------------
// xs[r] = 0.5*||Xb[r,:]||^2 from bf16
// ---------------------------------------------------------------------------
__global__ __launch_bounds__(256) void sk_row_norms(
    const unsigned short* __restrict__ Xb, float* __restrict__ XS)
{
    const int row  = blockIdx.x * 4 + (threadIdx.x >> 6);
    const int lane = threadIdx.x & 63;
    const unsigned int* p = (const unsigned int*)(Xb + (size_t)row * D_DIM);
    float s = 0.f;
    #pragma unroll
    for (int k = 0; k < 6; ++k) {
        const unsigned int u = p[lane + k * 64];
        const float f0 = __uint_as_float(u << 16);
        const float f1 = __uint_as_float(u & 0xffff0000u);
        s = fmaf(f0, f0, s); s = fmaf(f1, f1, s);
    }
    #pragma unroll
    for (int off = 32; off; off >>= 1) s += __shfl_xor(s, off, 64);
    if (lane == 0) XS[row] = 0.5f * s;
}

// ---------------------------------------------------------------------------
// Transpose+quant: QTu16 [2048 x 8192] -> Q8 (PERMUTED rows) [8192 x 2048] u8
// residual vs R32[i]. 64x64 tiles via LDS; output positions use p(c).
// ---------------------------------------------------------------------------
__global__ __launch_bounds__(256) void sk_transq(
    const unsigned short* __restrict__ QT, const int* __restrict__ R32,
    unsigned char* __restrict__ Q8)
{
    __shared__ unsigned short tile[64][72];
    const int tid = threadIdx.x;
    const int J0 = blockIdx.x * 64;   // logical j (cols of Q8)
    const int I0 = blockIdx.y * 64;   // i (rows of Q8)
    {
        const int tj = tid >> 2, ti = (tid & 3) * 16;
        const uint4* src = (const uint4*)(QT + (size_t)(J0 + tj) * N_PTS + I0 + ti);
        const uint4 a = src[0], b = src[1];
        *(uint4*)&tile[tj][ti] = a;
        *(uint4*)&tile[tj][ti + 8] = b;
    }
    __syncthreads();
    const int li = tid >> 2, lj = (tid & 3) * 16;
    const int R = R32[I0 + li];
    const int L0 = (J0 >> 2) & 63;      // 16-aligned
    const int t0 = J0 >> 8;
    unsigned char* orow = Q8 + (size_t)(I0 + li) * M_PTS;
    #pragma unroll
    for (int q = 0; q < 4; ++q) {
        unsigned char ob[4];
        #pragma unroll
        for (int e = 0; e < 4; ++e) {
            const int qv = (int)tile[lj + q * 4 + e][li];
            ob[e] = (unsigned char)fminf(fmaf((float)(qv - R), 1.0f / 12.0f, 0.5f), 255.f);
        }
        *(unsigned int*)(orow + 32 * (L0 + (lj >> 2) + q) + 4 * t0) =
            *(const unsigned int*)ob;
    }
}

// ---------------------------------------------------------------------------
// QTu16 -> QT8 (PERMUTED per 2048-col segment), residual vs R32[i]
// ---------------------------------------------------------------------------
__global__ __launch_bounds__(256) void sk_requant_qt(
    const unsigned short* __restrict__ QT, const int* __restrict__ R32,
    unsigned char* __restrict__ QT8)
{
    const size_t base = ((size_t)blockIdx.x * 256 + threadIdx.x) * 16;
    const int i0 = (int)(base & (size_t)(N_PTS - 1));   // 16-aligned
    const size_t rowb = base & ~(size_t)(N_PTS - 1);
    const uint4* src = (const uint4*)(QT + base);
    const uint4 a = src[0], b = src[1];
    unsigned int qs[8] = {a.x, a.y, a.z, a.w, b.x, b.y, b.z, b.w};
    const int* rp = R32 + i0;
    const int s  = i0 >> 11;
    const int ip = i0 & 2047;
    const int t  = ip >> 8;
    const int L0 = (ip >> 2) & 63;
    unsigned char* orow = QT8 + rowb + 2048 * s + 4 * t;
    #pragma unroll
    for (int q = 0; q < 4; ++q) {
        unsigned char ob[4];
        #pragma unroll
        for (int e = 0; e < 4; ++e) {
            const int k = q * 4 + e;
            const int qv = (int)((qs[k >> 1] >> ((k & 1) * 16)) & 0xffffu);
            ob[e] = (unsigned char)fminf(fmaf((float)(qv - rp[k]), 1.0f / 12.0f, 0.5f), 255.f);
        }
        *(unsigned int*)(orow + 32 * (L0 + q)) = *(const unsigned int*)ob;
    }
}

// ---------------------------------------------------------------------------
// F softmin over permuted Q8 rows (2048 cols). 8 rows/block (1 wave/row),
// 512 thr, 1024 blocks. hb loads coalesced: hb4[64t + lane].
// non-final: hbG[i] = la[i] - LSE_res ; final: FO[i] = eps*(R_i - LSE_res)
// ---------------------------------------------------------------------------
template<bool FINAL>
__global__ __launch_bounds__(512) void sk_smF(
    const unsigned char* __restrict__ Q8, const float* __restrict__ hbF,
    const float* __restrict__ LW, const int* __restrict__ R32,
    float* __restrict__ outv)
{
    const int tid = threadIdx.x, wave = tid >> 6, lane = tid & 63;
    float hbr[32];
    const float4* hb4 = (const float4*)hbF;
    #pragma unroll
    for (int t = 0; t < 8; ++t) {
        const float4 v = hb4[t * 64 + lane];
        hbr[t * 4 + 0] = v.x; hbr[t * 4 + 1] = v.y;
        hbr[t * 4 + 2] = v.z; hbr[t * 4 + 3] = v.w;
    }
    const int row = blockIdx.x * 8 + wave;
    const uint4* qp = (const uint4*)(Q8 + (size_t)row * M_PTS);
    const uint4 q0 = qp[lane * 2], q1 = qp[lane * 2 + 1];
    float m, s;
    sk_lse32(q0, q1, hbr, m, s);
    #pragma unroll
    for (int off = 1; off < 64; off <<= 1) {
        const float m2 = __shfl_xor(m, off, 64);
        const float s2 = __shfl_xor(s, off, 64);
        sk_merge(m, s, m2, s2);
    }
    if (lane == 0) {
        const float lse = m + __logf(s);
        if (FINAL) outv[row] = EPS_F * ((float)R32[row] * U16_TO_NAT - lse);
        else       outv[row] = LW[row] - lse;
    }
}

// ---------------------------------------------------------------------------
// G softmin over permuted QT8 rows (8192 cols = 4 segments). 4 rows/block,
// 512 thr (8 waves), 2 waves/row (2 segments each), LDS merge.
// writes hbF[j] = lb[j] - LSE_res
// ---------------------------------------------------------------------------
__global__ __launch_bounds__(512) void sk_smG(
    const unsigned char* __restrict__ QT8, const float* __restrict__ hbG,
    const float* __restrict__ LW, float* __restrict__ hbF)
{
    __shared__ float mred[4], sred[4];
    const int tid = threadIdx.x, wave = tid >> 6, lane = tid & 63;
    const int rloc = wave >> 1, half = wave & 1;
    const int row = blockIdx.x * 4 + rloc;
    const uint4* qp = (const uint4*)(QT8 + (size_t)row * N_PTS);
    const float4* hb4 = (const float4*)hbG;
    float m = -INFINITY, s = 0.f;
    #pragma unroll
    for (int ss = 0; ss < 2; ++ss) {
        const int seg = half * 2 + ss;
        float hbr[32];
        #pragma unroll
        for (int t = 0; t < 8; ++t) {
            const float4 v = hb4[seg * 512 + t * 64 + lane];
            hbr[t * 4 + 0] = v.x; hbr[t * 4 + 1] = v.y;
            hbr[t * 4 + 2] = v.z; hbr[t * 4 + 3] = v.w;
        }
        const uint4 q0 = qp[seg * 128 + lane * 2];
        const uint4 q1 = qp[seg * 128 + lane * 2 + 1];
        float mc, sc;
        sk_lse32(q0, q1, hbr, mc, sc);
        sk_merge(m, s, mc, sc);
    }
    #pragma unroll
    for (int off = 1; off < 64; off <<= 1) {
        const float m2 = __shfl_xor(m, off, 64);
        const float s2 = __shfl_xor(s, off, 64);
        sk_merge(m, s, m2, s2);
    }
    if (half == 1 && lane == 0) { mred[rloc] = m; sred[rloc] = s; }
    __syncthreads();
    if (half == 0 && lane == 0) {
        sk_merge(m, s, mred[rloc], sred[rloc]);
        hbF[row] = LW[N_PTS + row] - (m + __logf(s));
    }
}

// ---------------------------------------------------------------------------
// S = <h, FO + eps*la/2> + <hi, eps*(hbF - lb/2)>; out = exp(-S)
// ---------------------------------------------------------------------------
__global__ __launch_bounds__(1024) void sk_finalize(
    const float* __restrict__ fo, const float* __restrict__ hbF,
    const float* __restrict__ h, const float* __restrict__ hi,
    const float* __restrict__ lw, float* __restrict__ out)
{
    const int tid = threadIdx.x;
    float acc = 0.f;
    for (int r = tid; r < N_PTS; r += 1024)
        acc += h[r] * (fo[r] + 0.5f * EPS_F * lw[r]);
    for (int j = tid; j < M_PTS; j += 1024)
        acc += hi[j] * EPS_F * (hbF[j] - 0.5f * lw[N_PTS + j]);
    __shared__ float red[1024];
    red[tid] = acc;
    __syncthreads();
    for (int st = 512; st; st >>= 1) {
        if (tid < st) red[tid] += red[tid + st];
        __syncthreads();
    }
    if (tid == 0) out[0] = expf(-red[0]);
}

// ---------------------------------------------------------------------------
extern "C" void kernel_launch(void* const* d_in, const int* in_sizes, int n_in,
                              void* d_out, int out_size, void* d_ws, size_t ws_size,
                              hipStream_t stream)
{
    const float* dpts = (const float*)d_in[0];
    const float* spts = (const float*)d_in[1];
    const float* h    = (const float*)d_in[2];
    const float* hiw  = (const float*)d_in[3];
    const float* W    = (const float*)d_in[4];
    float* out = (float*)d_out;

    float* XS  = (float*)d_ws;                        // NM
    float* LW  = XS + NM_PTS;                         // NM (la | lb)
    float* HBF = LW + NM_PTS;                         // M
    float* HBG = HBF + M_PTS;                         // N
    float* FO  = HBG + N_PTS;                         // N
    int*   R32 = (int*)(FO + N_PTS);                  // N
    unsigned short* Db = (unsigned short*)(R32 + N_PTS);        // NM x D bf16
    unsigned short* Wb = Db + (size_t)NM_PTS * D_DIM;           // D x D bf16
    unsigned short* Xb = Wb + (size_t)D_DIM * D_DIM;            // NM x D bf16
    unsigned short* QTu = Xb + (size_t)NM_PTS * D_DIM;          // M x N u16
    unsigned char*  Q8  = (unsigned char*)(QTu + (size_t)M_PTS * N_PTS); // N x M u8
    unsigned char*  QT8 = Q8 + (size_t)N_PTS * M_PTS;           // M x N u8

    sk_init<<<NM_PTS / 256, 256, 0, stream>>>(h, hiw, LW, HBF, R32);

    sk_cast<<<(size_t)N_PTS * D_DIM / 1024, 256, 0, stream>>>(dpts, Db);
    sk_cast<<<(size_t)M_PTS * D_DIM / 1024, 256, 0, stream>>>(
        spts, Db + (size_t)N_PTS * D_DIM);
    sk_cast<<<(size_t)D_DIM * D_DIM / 1024, 256, 0, stream>>>(W, Wb);

    sk_mfma<0><<<dim3(D_DIM / 128, NM_PTS / 128), 256, 0, stream>>>(
        Db, Wb, Xb, nullptr, nullptr, nullptr, nullptr);

    sk_row_norms<<<NM_PTS / 4, 256, 0, stream>>>(Xb, XS);

    sk_mfma<1><<<dim3(M_PTS / 128, N_PTS / 128), 256, 0, stream>>>(
        Xb, Xb + (size_t)N_PTS * D_DIM, nullptr, QTu, R32, XS, XS + N_PTS);

    sk_transq<<<dim3(M_PTS / 64, N_PTS / 64), 256, 0, stream>>>(QTu, R32, Q8);
    sk_requant_qt<<<(size_t)M_PTS * N_PTS / 4096, 256, 0, stream>>>(QTu, R32, QT8);

    for (int it = 0; it < SINK_ITERS; ++it) {
        sk_smF<false><<<N_PTS / 8, 512, 0, stream>>>(Q8, HBF, LW, R32, HBG);
        sk_smG       <<<M_PTS / 4, 512, 0, stream>>>(QT8, HBG, LW, HBF);
    }
    sk_smF<true><<<N_PTS / 8, 512, 0, stream>>>(Q8, HBF, LW, R32, FO);

    sk_finalize<<<1, 1024, 0, stream>>>(FO, HBF, h, hiw, LW, out);
}